// Round 1
// 325.016 us; speedup vs baseline: 1.0743x; 1.0743x over previous
//
#include <hip/hip_runtime.h>

// ---------------------------------------------------------------------------
// AttentionTemporalEncoder on MI355X (gfx950)
// B=32, T=512, HIDDEN=1024, NH=16, HD=64
//
// R14 change: gemm1/gemm2 ported from 128^2 2-barrier structure to a
// 256x256 8-wave 8-phase mainloop (HK/m201-style):
//  - BK=64, double-buffered LDS (128 KiB), half-tile (128-row) staging via
//    global_load_lds width=16, granule-XOR swizzle on the global source.
//  - per phase: {ds_read frag subtile | issue 1 half-tile stage | bar |
//    lgkmcnt(0) | setprio(1) 16xMFMA setprio(0) | vmcnt(10) | bar}.
//    Counted vmcnt keeps 5 half-tiles in flight; never drains to 0 in the
//    steady loop; peeled last iteration drains 10->8->6->4->2->0.
//  - grids: gemm1 768x512 (3 exact CU-waves), gemm2 256x512, XCD-clustered
//    so all m-tiles sharing an activation panel run on one XCD.
// prep / attn / final byte-identical to R13.
// ---------------------------------------------------------------------------

typedef _Float16 half8 __attribute__((ext_vector_type(8)));
typedef _Float16 half4 __attribute__((ext_vector_type(4)));
typedef float floatx4 __attribute__((ext_vector_type(4)));
typedef unsigned uintx2 __attribute__((ext_vector_type(2)));

#define HID 1024
#define TT 512
#define NB 32
#define QSCALE 0.1803368801111244f   /* 0.125 * log2(e) */
#define SB2 72.13475204444817f       /* 50 * log2(e)    */

__device__ __forceinline__ void gload16(const void* g, void* l) {
    __builtin_amdgcn_global_load_lds(
        (const __attribute__((address_space(1))) unsigned int*)g,
        (__attribute__((address_space(3))) unsigned int*)l, 16, 0, 0);
}

// monotone float->uint key: preserves order for atomicMax; 0 is below all keys
__device__ __forceinline__ unsigned fkey(float f) {
    unsigned u = __float_as_uint(f);
    return (u & 0x80000000u) ? ~u : (u | 0x80000000u);
}
__device__ __forceinline__ float funkey(unsigned k) {
    unsigned u = (k & 0x80000000u) ? (k ^ 0x80000000u) : ~k;
    return __uint_as_float(u);
}

// ---------------------------------------------------------------------------
// prep: [0,4096) convw (Q sec pre-scaled, float4->half4),
//       [4096,8192) xpose 64x64, [8192,8320) initmax, [8320,8324) bqs.
__global__ __launch_bounds__(256) void prep_kernel(
    const float* __restrict__ Wq, const float* __restrict__ Wk,
    const float* __restrict__ Wv, const float* __restrict__ Wo,
    _Float16* __restrict__ Wcat,
    const float* __restrict__ x, _Float16* __restrict__ xT,
    unsigned* __restrict__ omax,
    const float* __restrict__ bq, float* __restrict__ bqs)
{
    __shared__ float tile[64][65];
    const int bid = blockIdx.x;
    if (bid < 4096) {
        int i4 = bid * 256 + threadIdx.x;        // float4 index, 0 .. 1M
        int sec = i4 >> 18;
        int off4 = i4 & ((1 << 18) - 1);
        const float* src = (sec == 0) ? Wq : (sec == 1) ? Wk
                          : (sec == 2) ? Wv : Wo;
        float4 v = ((const float4*)src)[off4];
        if (sec == 0) {
            v.x *= QSCALE; v.y *= QSCALE; v.z *= QSCALE; v.w *= QSCALE;
        }
        half4 h = {(_Float16)v.x, (_Float16)v.y, (_Float16)v.z, (_Float16)v.w};
        *(half4*)(Wcat + (size_t)i4 * 4) = h;
    } else if (bid < 8192) {
        int idx = bid - 4096;                    // 32 b x 16 h-tiles x 8 t-tiles
        int b = idx >> 7, h0 = ((idx >> 3) & 15) * 64, t0 = (idx & 7) * 64;
        int tx = threadIdx.x & 15, ty = threadIdx.x >> 4;   // 16x16
        const float* xb = x + ((size_t)b * HID + h0) * TT + t0;
        for (int p = 0; p < 4; p++) {
            int r = ty + 16 * p;
            float4 v = *(const float4*)(xb + (size_t)r * TT + tx * 4);
            tile[r][tx * 4 + 0] = v.x;
            tile[r][tx * 4 + 1] = v.y;
            tile[r][tx * 4 + 2] = v.z;
            tile[r][tx * 4 + 3] = v.w;
        }
        __syncthreads();
        int hc = (threadIdx.x & 7) * 8, tb = threadIdx.x >> 3;  // 8 x 32
        for (int rd = 0; rd < 2; rd++) {
            int tt = tb + 32 * rd;
            half8 pk;
            for (int k = 0; k < 8; k++)
                pk[k] = (_Float16)tile[hc + k][tt];
            *(half8*)(xT + ((size_t)b * TT + t0 + tt) * HID + h0 + hc) = pk;
        }
    } else if (bid < 8320) {
        omax[(bid - 8192) * 256 + threadIdx.x] = 0u;
    } else {
        int i = (bid - 8320) * 256 + threadIdx.x;   // 0..1023
        bqs[i] = bq[i] * QSCALE;
    }
}

// ---------------------------------------------------------------------------
// 256x256 8-phase mainloop. C(256x256) += A(256xK) * B^T, both row-major,
// K contiguous, lda = ldb = 1024. 512 threads = 8 waves (2M x 4N), per-wave
// output 128x64 = acc[8][4]. LDS 128 KiB: A[buf][mh][128][64], B[buf][nh]
// [128][64] halves, granule-XOR swizzled via pre-swizzled global source.
//
// Phase schedule per iteration (2 K-tiles: buf0 then buf1), staging one
// half-tile per phase into regions whose reads completed the phase before:
//   P1 (b0,mh0,nh0) stage b1.A.mh1@cur   P5 (b1,mh0,nh0) stage b0.A.mh1@nxt
//   P2 (b0,mh0,nh1) stage b0.A.mh0@nxt   P6 (b1,mh0,nh1) stage b1.A.mh0@nxt
//   P3 (b0,mh1,nh1) stage b0.B.nh0@nxt   P7 (b1,mh1,nh1) stage b1.B.nh0@nxt
//   P4 (b0,mh1,nh0) stage b0.B.nh1@nxt   P8 (b1,mh1,nh0) stage b1.B.nh1@nxt
// Uniform vmcnt(10) at each phase tail satisfies every read deadline
// (verified by load-ordinal accounting; 2 loads per thread per half-tile).

#define PH_PRE do { \
    __builtin_amdgcn_s_barrier(); \
    asm volatile("s_waitcnt lgkmcnt(0)" ::: "memory"); \
    __builtin_amdgcn_sched_barrier(0); \
    __builtin_amdgcn_s_setprio(1); \
} while (0)

#define PH_POST(N) do { \
    __builtin_amdgcn_s_setprio(0); \
    asm volatile("s_waitcnt vmcnt(" #N ")" ::: "memory"); \
    __builtin_amdgcn_s_barrier(); \
} while (0)

#define LDA(P, MH) do { \
    const _Float16* ab_ = lds + (P) * 16384 + (MH) * 8192 + aoff; \
    af[0][0] = *(const half8*)(ab_ + pb0); \
    af[0][1] = *(const half8*)(ab_ + pb1); \
    af[1][0] = *(const half8*)(ab_ + 1024 + pb0); \
    af[1][1] = *(const half8*)(ab_ + 1024 + pb1); \
    af[2][0] = *(const half8*)(ab_ + 2048 + pb0); \
    af[2][1] = *(const half8*)(ab_ + 2048 + pb1); \
    af[3][0] = *(const half8*)(ab_ + 3072 + pb0); \
    af[3][1] = *(const half8*)(ab_ + 3072 + pb1); \
} while (0)

#define LDB(P, NH) do { \
    const _Float16* bb_ = lds + 32768 + (P) * 16384 + (NH) * 8192 + boff; \
    bf[NH][0][0] = *(const half8*)(bb_ + pb0); \
    bf[NH][0][1] = *(const half8*)(bb_ + pb1); \
    bf[NH][1][0] = *(const half8*)(bb_ + 1024 + pb0); \
    bf[NH][1][1] = *(const half8*)(bb_ + 1024 + pb1); \
} while (0)

#define STAGE_A(P, MH, K0) do { \
    _Float16* d_ = lds + (P) * 16384 + (MH) * 8192 + wst; \
    gload16(ag + (MH) * 64 * 1024 + (K0), d_); \
    gload16(ag + (128 + (MH) * 64) * 1024 + (K0), d_ + 4096); \
} while (0)

#define STAGE_B(P, NH, K0) do { \
    _Float16* d_ = lds + 32768 + (P) * 16384 + (NH) * 8192 + wst; \
    gload16(bg + (NH) * 32 * 1024 + (K0), d_); \
    gload16(bg + (128 + (NH) * 32) * 1024 + (K0), d_ + 4096); \
} while (0)

#define MFMAQ(MH, NH) do { \
    _Pragma("unroll") \
    for (int j_ = 0; j_ < 4; ++j_) { \
        _Pragma("unroll") \
        for (int n_ = 0; n_ < 2; ++n_) { \
            floatx4 c_ = acc[(MH) * 4 + j_][(NH) * 2 + n_]; \
            c_ = __builtin_amdgcn_mfma_f32_16x16x32_f16( \
                af[j_][0], bf[NH][n_][0], c_, 0, 0, 0); \
            c_ = __builtin_amdgcn_mfma_f32_16x16x32_f16( \
                af[j_][1], bf[NH][n_][1], c_, 0, 0, 0); \
            acc[(MH) * 4 + j_][(NH) * 2 + n_] = c_; \
        } \
    } \
} while (0)

__device__ __forceinline__ void mainloop256(
    const _Float16* __restrict__ Ag,   // A + m0*1024 (rows m, K contig)
    const _Float16* __restrict__ Bg,   // act + n0*1024 (rows n, K contig)
    _Float16* lds, floatx4 acc[8][4], int tid)
{
    const int lane = tid & 63;
    const int w = tid >> 6, wr = w >> 2, wc = w & 3;
    const int l15 = lane & 15, quad = lane >> 4;
    const int pa = quad ^ (l15 & 7);
    const int pb0 = pa * 8, pb1 = (pa ^ 4) * 8;
    const int aoff = (wr * 64 + l15) * 64;
    const int boff = (wc * 32 + l15) * 64;
    const int wst = w * 512;                    // wave-uniform LDS stage base
    const int r = tid >> 3;                     // 0..63
    const int sg = (tid & 7) ^ (r & 7);         // pre-swizzled source granule
    const int nbase = ((r >> 5) << 6) + (r & 31);
    const _Float16* ag = Ag + (size_t)r * 1024 + sg * 8;
    const _Float16* bg = Bg + (size_t)nbase * 1024 + sg * 8;

    half8 af[4][2], bf[2][2][2];

    // prologue: k-tile 0 fully + k-tile 1 minus A.mh1 (staged at P1)
    STAGE_A(0, 0, 0); STAGE_B(0, 0, 0); STAGE_B(0, 1, 0); STAGE_A(0, 1, 0);
    STAGE_A(1, 0, 64); STAGE_B(1, 0, 64); STAGE_B(1, 1, 64);
    asm volatile("s_waitcnt vmcnt(10)" ::: "memory");
    __builtin_amdgcn_s_barrier();

    for (int i = 0; i < 7; ++i) {
        const int kb = i * 128 + 64;
        const int kn0 = kb + 64, kn1 = kb + 128;
        LDA(0, 0); LDB(0, 0); STAGE_A(1, 1, kb);
        PH_PRE; MFMAQ(0, 0); PH_POST(10);
        LDB(0, 1);            STAGE_A(0, 0, kn0);
        PH_PRE; MFMAQ(0, 1); PH_POST(10);
        LDA(0, 1);            STAGE_B(0, 0, kn0);
        PH_PRE; MFMAQ(1, 1); PH_POST(10);
                              STAGE_B(0, 1, kn0);
        PH_PRE; MFMAQ(1, 0); PH_POST(10);
        LDA(1, 0); LDB(1, 0); STAGE_A(0, 1, kn0);
        PH_PRE; MFMAQ(0, 0); PH_POST(10);
        LDB(1, 1);            STAGE_A(1, 0, kn1);
        PH_PRE; MFMAQ(0, 1); PH_POST(10);
        LDA(1, 1);            STAGE_B(1, 0, kn1);
        PH_PRE; MFMAQ(1, 1); PH_POST(10);
                              STAGE_B(1, 1, kn1);
        PH_PRE; MFMAQ(1, 0); PH_POST(10);
    }
    // peeled last iteration (k-tiles 14 @896 buf0, 15 @960 buf1): drain
    LDA(0, 0); LDB(0, 0); STAGE_A(1, 1, 960);
    PH_PRE; MFMAQ(0, 0); PH_POST(10);
    LDB(0, 1);
    PH_PRE; MFMAQ(0, 1); PH_POST(8);
    LDA(0, 1);
    PH_PRE; MFMAQ(1, 1); PH_POST(6);
    PH_PRE; MFMAQ(1, 0); PH_POST(4);
    LDA(1, 0); LDB(1, 0);
    PH_PRE; MFMAQ(0, 0); PH_POST(2);
    LDB(1, 1);
    PH_PRE; MFMAQ(0, 1); PH_POST(0);
    LDA(1, 1);
    PH_PRE; MFMAQ(1, 1); MFMAQ(1, 0);
    __builtin_amdgcn_s_setprio(0);
}

// gemm1 (merged q/k/v). 1-D grid 768, XCD-clustered: grp = (n0i,b) pinned to
// xcd = grp%8; 12 m-tiles inner so the 512 KB xT panel is fetched once/XCD.
__global__ __launch_bounds__(512, 2) void gemm1_kernel(
    const _Float16* __restrict__ Wcat,
    const float* __restrict__ bqs, const float* __restrict__ bk,
    const float* __restrict__ bv,
    const _Float16* __restrict__ xT,
    _Float16* __restrict__ QT, _Float16* __restrict__ KT,
    _Float16* __restrict__ Vb)
{
    __shared__ __align__(16) _Float16 smem[65536];   // 128 KiB
    const int tid = threadIdx.x;
    const int id = blockIdx.x;
    const int xcd = id & 7, slot = id >> 3;      // slot 0..95
    const int grp = xcd + 8 * (slot / 12);       // 0..63 = n0i + 2*b
    const int m0 = (slot % 12) * 256;
    const int n0 = (grp & 1) * 256;
    const int bb = grp >> 1;
    const int lane = tid & 63;
    const int w = tid >> 6, wr = w >> 2, wc = w & 3;
    const int l15 = lane & 15, quad = lane >> 4;

    floatx4 acc[8][4] = {};
    mainloop256(Wcat + (size_t)m0 * 1024,
                xT + ((size_t)bb * TT + n0) * HID, smem, acc, tid);
    __syncthreads();

    const int sec = m0 >> 10;          // 0=q 1=k 2=v (uniform per block)
    const int mo = m0 & 1023;

    if (sec < 2) {
        const float* bias = (sec == 0) ? bqs : bk;
        _Float16* dst = (sec == 0) ? QT : KT;
        _Float16* tr = smem;                       // [256][136] halves
        for (int h = 0; h < 2; ++h) {
            if (wr == h) {
                for (int mi = 0; mi < 8; ++mi) {
                    float bs[4];
                    for (int rr = 0; rr < 4; ++rr)
                        bs[rr] = bias[mo + h * 128 + mi * 16 + quad * 4 + rr];
                    for (int ni = 0; ni < 4; ++ni) {
                        half4 pk;
                        for (int rr = 0; rr < 4; ++rr)
                            pk[rr] = (_Float16)(acc[mi][ni][rr] + bs[rr]);
                        *(half4*)(tr + (wc * 64 + ni * 16 + l15) * 136 +
                                  mi * 16 + quad * 4) = pk;
                    }
                }
            }
            __syncthreads();
            const int row = tid >> 4, off = (tid & 15) * 8;
            for (int s = 0; s < 8; ++s) {
                uint4 v = *(uint4*)(tr + (row + 32 * s) * 136 + off);
                *(uint4*)(dst + ((size_t)bb * TT + n0 + row + 32 * s) * HID +
                          mo + h * 128 + off) = v;
            }
            __syncthreads();
        }
    } else {
        for (int mi = 0; mi < 8; ++mi) {
            float bs[4];
            for (int rr = 0; rr < 4; ++rr)
                bs[rr] = bv[mo + wr * 128 + mi * 16 + quad * 4 + rr];
            for (int ni = 0; ni < 4; ++ni) {
                int t = n0 + wc * 64 + ni * 16 + l15;
                for (int rr = 0; rr < 4; ++rr) {
                    int o = mo + wr * 128 + mi * 16 + quad * 4 + rr;
                    Vb[((size_t)bb * HID + o) * TT + t] =
                        (_Float16)(acc[mi][ni][rr] + bs[rr]);
                }
            }
        }
    }
}

// ---------------------------------------------------------------------------
// attention (R9 inner loops, unchanged). 1-D grid 2048, XCD-clustered.
__global__ __launch_bounds__(256) void attn_kernel(
    const _Float16* __restrict__ QT, const _Float16* __restrict__ KT,
    const _Float16* __restrict__ Vb, const int* __restrict__ mask,
    _Float16* __restrict__ OcT)
{
    __shared__ __align__(16) _Float16 kvbuf[4 * 4096];
    __shared__ __align__(16) _Float16 ps[2 * 4096];  // [qt][q][t] swizzled
    __shared__ __align__(16) float msf[2][64];       // clamp hi bound per t

    const int id = blockIdx.x;
    const int xcd = id & 7, slot = id >> 3;      // slot 0..255
    const int grp = xcd + 8 * (slot >> 2);       // 0..511 = hd + 16*b
    const int q0 = (slot & 3) * 128;
    const int hd = grp & 15, b = grp >> 4;
    const int tid = threadIdx.x;
    const int lane = tid & 63, wid = tid >> 6;
    const int l15 = lane & 15, quad = lane >> 4;

    const _Float16* QTb = QT + ((size_t)b * TT + q0) * HID + hd * 64;
    const _Float16* KTb = KT + (size_t)b * TT * HID + hd * 64;
    const _Float16* Vbb = Vb + ((size_t)b * HID + hd * 64) * TT;
    const int* mb = mask + b * TT;

    const int srow = lane >> 3;                 // 0..7 == row&7
    const int sg = (lane & 7) ^ srow;
    const int pa = quad ^ (l15 & 7);
    const int pz = l15 & 7;

    for (int qt = 0; qt < 2; qt++)
        for (int p = 0; p < 2; p++) {
            int r = p * 32 + wid * 8 + srow;
            gload16(QTb + (size_t)(qt * 64 + r) * HID + sg * 8,
                    kvbuf + qt * 4096 + (p * 32 + wid * 8) * 64);
        }
    __syncthreads();
    half8 bq[2][2];
    for (int qt = 0; qt < 2; qt++) {
        bq[qt][0] = *(half8*)(kvbuf + qt * 4096 + (wid * 16 + l15) * 64 + pa * 8);
        bq[qt][1] = *(half8*)(kvbuf + qt * 4096 + (wid * 16 + l15) * 64 + (pa ^ 4) * 8);
    }
    __syncthreads();

    auto stage = [&](int jcn, int bufn) {
        int t0n = jcn * 64;
        _Float16* kd = kvbuf + bufn * 4096;
        _Float16* vd = kvbuf + (2 + bufn) * 4096;
        for (int p = 0; p < 2; p++) {
            int r = p * 32 + wid * 8 + srow;
            gload16(KTb + (size_t)(t0n + r) * HID + sg * 8,
                    kd + (p * 32 + wid * 8) * 64);
            gload16(Vbb + (size_t)r * TT + t0n + sg * 8,
                    vd + (p * 32 + wid * 8) * 64);
        }
        if (tid < 64) msf[bufn][tid] = mb[t0n + tid] ? SB2 : -SB2;
    };

    stage(0, 0);

    floatx4 oacc[2][4] = {};
    float rs[2] = {0.f, 0.f};
    const float lo = -SB2;

    for (int jc = 0; jc < 8; jc++) {
        const int cur = jc & 1;
        __syncthreads();
        if (jc < 7) stage(jc + 1, 1 - cur);

        const _Float16* ks = kvbuf + cur * 4096;
        const _Float16* vs = kvbuf + (2 + cur) * 4096;

        for (int jt = 0; jt < 4; jt++) {
            half8 ka0 = *(half8*)(ks + (jt * 16 + l15) * 64 + pa * 8);
            half8 ka1 = *(half8*)(ks + (jt * 16 + l15) * 64 + (pa ^ 4) * 8);
            floatx4 hi = *(floatx4*)(&msf[cur][jt * 16 + quad * 4]);
            for (int qt = 0; qt < 2; qt++) {
                floatx4 sc = {0.f, 0.f, 0.f, 0.f};
                sc = __builtin_amdgcn_mfma_f32_16x16x32_f16(ka0, bq[qt][0], sc, 0, 0, 0);
                sc = __builtin_amdgcn_mfma_f32_16x16x32_f16(ka1, bq[qt][1], sc, 0, 0, 0);
                float e0 = __builtin_amdgcn_exp2f(fminf(fmaxf(sc[0], lo), hi[0]));
                float e1 = __builtin_amdgcn_exp2f(fminf(fmaxf(sc[1], lo), hi[1]));
                float e2 = __builtin_amdgcn_exp2f(fminf(fmaxf(sc[2], lo), hi[2]));
                float e3 = __builtin_amdgcn_exp2f(fminf(fmaxf(sc[3], lo), hi[3]));
                rs[qt] += (e0 + e1) + (e2 + e3);
                unsigned uA = __builtin_bit_cast(
                    unsigned, __builtin_amdgcn_cvt_pkrtz(e0, e1));
                unsigned uB = __builtin_bit_cast(
                    unsigned, __builtin_amdgcn_cvt_pkrtz(e2, e3));
                uintx2 uv = {uA, uB};
                half4 pk = __builtin_bit_cast(half4, uv);
                int g = jt * 2 + (quad >> 1);
                *(half4*)(ps + qt * 4096 + (wid * 16 + l15) * 64 + (g ^ pz) * 8 +
                          (quad & 1) * 4) = pk;
            }
        }
        for (int kc = 0; kc < 2; kc++) {
            int g = kc * 4 + quad;
            half8 bv8[4];
            for (int d4 = 0; d4 < 4; d4++)
                bv8[d4] = *(half8*)(vs + (d4 * 16 + l15) * 64 + (g ^ pz) * 8);
            for (int qt = 0; qt < 2; qt++) {
                half8 ap = *(half8*)(ps + qt * 4096 + (wid * 16 + l15) * 64 +
                                     (g ^ pz) * 8);
                for (int d4 = 0; d4 < 4; d4++)
                    oacc[qt][d4] = __builtin_amdgcn_mfma_f32_16x16x32_f16(
                        ap, bv8[d4], oacc[qt][d4], 0, 0, 0);
            }
        }
    }

    for (int qt = 0; qt < 2; qt++) {
        float s = rs[qt];
        s += __shfl_xor(s, 16, 64);
        s += __shfl_xor(s, 32, 64);
        s = 1.0f / s;
        float inv[4];
        for (int r = 0; r < 4; r++) inv[r] = __shfl(s, quad * 4 + r, 64);
        for (int d4 = 0; d4 < 4; d4++)
            for (int r = 0; r < 4; r++) {
                int t = q0 + qt * 64 + wid * 16 + quad * 4 + r;
                int c = hd * 64 + d4 * 16 + l15;
                OcT[((size_t)b * TT + t) * HID + c] =
                    (_Float16)(oacc[qt][d4][r] * inv[r]);
            }
    }
}

// ---------------------------------------------------------------------------
// gemm2. 1-D grid 256, XCD-clustered (4 m-tiles per n-group).
__global__ __launch_bounds__(512, 2) void gemm2_kernel(
    const _Float16* __restrict__ Wo16, const _Float16* __restrict__ OcT,
    unsigned* __restrict__ omax)
{
    __shared__ __align__(16) _Float16 smem[65536];
    const int tid = threadIdx.x;
    const int id = blockIdx.x;
    const int xcd = id & 7, slot = id >> 3;      // slot 0..31
    const int grp = xcd + 8 * (slot >> 2);       // 0..63 = n0i + 2*b
    const int m0 = (slot & 3) * 256;
    const int n0 = (grp & 1) * 256;
    const int bb = grp >> 1;
    const int lane = tid & 63;
    const int w = tid >> 6, wr = w >> 2;
    const int l15 = lane & 15, quad = lane >> 4;

    floatx4 acc[8][4] = {};
    mainloop256(Wo16 + (size_t)m0 * 1024,
                OcT + ((size_t)bb * TT + n0) * HID, smem, acc, tid);

    for (int mi = 0; mi < 8; ++mi)
        for (int rr = 0; rr < 4; ++rr) {
            float v = acc[mi][0][rr];
            v = fmaxf(v, acc[mi][1][rr]);
            v = fmaxf(v, acc[mi][2][rr]);
            v = fmaxf(v, acc[mi][3][rr]);
            for (int d = 1; d < 16; d <<= 1)
                v = fmaxf(v, __shfl_xor(v, d, 64));
            if (l15 == 0) {
                int o = m0 + wr * 128 + mi * 16 + quad * 4 + rr;
                atomicMax(&omax[bb * HID + o], fkey(v));
            }
        }
}

__global__ __launch_bounds__(256) void final_kernel(
    const unsigned* __restrict__ omax, const float* __restrict__ bo,
    float* __restrict__ out)
{
    int i = blockIdx.x * 256 + threadIdx.x;   // 0 .. 32767
    out[i] = funkey(omax[i]) + bo[i & 1023];
}

// ---------------------------------------------------------------------------
extern "C" void kernel_launch(void* const* d_in, const int* in_sizes, int n_in,
                              void* d_out, int out_size, void* d_ws, size_t ws_size,
                              hipStream_t stream)
{
    const float* x  = (const float*)d_in[0];
    const int* mask = (const int*)d_in[1];
    const float* Wq = (const float*)d_in[2];
    const float* bq = (const float*)d_in[3];
    const float* Wk = (const float*)d_in[4];
    const float* bk = (const float*)d_in[5];
    const float* Wv = (const float*)d_in[6];
    const float* bv = (const float*)d_in[7];
    const float* Wo = (const float*)d_in[8];
    const float* bo = (const float*)d_in[9];
    float* out = (float*)d_out;

    char* ws = (char*)d_ws;
    _Float16* Wcat = (_Float16*)(ws);                      //   8 MiB (q,k,v,o)
    _Float16* xT   = (_Float16*)(ws + (8ull  << 20));      //  32 MiB
    _Float16* QT   = (_Float16*)(ws + (40ull << 20));      //  32 MiB
    _Float16* KT   = (_Float16*)(ws + (72ull << 20));      //  32 MiB
    _Float16* Vb   = (_Float16*)(ws + (104ull << 20));     //  32 MiB
    _Float16* OcT  = (_Float16*)(ws + (136ull << 20));     //  32 MiB
    unsigned* omax = (unsigned*)(ws + (168ull << 20));     // 128 KiB
    float*    bqs  = (float*)(ws + (168ull << 20) + (128ull << 10)); // 4 KiB

    prep_kernel<<<8324, 256, 0, stream>>>(Wq, Wk, Wv, Wo, Wcat, x, xT, omax,
                                          bq, bqs);
    gemm1_kernel<<<768, 512, 0, stream>>>(Wcat, bqs, bk, bv, xT, QT, KT, Vb);
    attn_kernel<<<2048, 256, 0, stream>>>(QT, KT, Vb, mask, OcT);
    gemm2_kernel<<<256, 512, 0, stream>>>(Wcat + (3ull << 20), OcT, omax);
    final_kernel<<<128, 256, 0, stream>>>(omax, bo, out);
}

// Round 2
// 315.769 us; speedup vs baseline: 1.1057x; 1.0293x over previous
//
#include <hip/hip_runtime.h>

// ---------------------------------------------------------------------------
// AttentionTemporalEncoder on MI355X (gfx950)
// B=32, T=512, HIDDEN=1024, NH=16, HD=64
//
// R15 change: chained persistent gemm1.
//  - grid 256 (1 block/CU): each block owns (n0,b) and 3 consecutive m-tiles,
//    run as ONE virtual 48-K-tile 8-phase pipeline (no drain/refill at tile
//    boundaries; stage addr selects m-slice via (j>>4)*256 rows, B k = j&15).
//  - LDS-free epilogue: Q/K written with direct half4 scattered stores
//    (Vb-style; TCC merges to full lines), so boundary epilogues run inside
//    the live pipeline. Store ordinals only over-wait counted vmcnt (retire
//    is in issue order) - ledger unchanged from R14's verified schedule.
//  - one prologue fill + one drain per block instead of three; tr-transpose
//    epilogue (4 syncthreads, half-wave-serialized) removed entirely.
// gemm2 keeps the R14 256x256 8-phase mainloop; prep/attn/final unchanged.
// ---------------------------------------------------------------------------

typedef _Float16 half8 __attribute__((ext_vector_type(8)));
typedef _Float16 half4 __attribute__((ext_vector_type(4)));
typedef float floatx4 __attribute__((ext_vector_type(4)));
typedef unsigned uintx2 __attribute__((ext_vector_type(2)));

#define HID 1024
#define TT 512
#define NB 32
#define QSCALE 0.1803368801111244f   /* 0.125 * log2(e) */
#define SB2 72.13475204444817f       /* 50 * log2(e)    */

__device__ __forceinline__ void gload16(const void* g, void* l) {
    __builtin_amdgcn_global_load_lds(
        (const __attribute__((address_space(1))) unsigned int*)g,
        (__attribute__((address_space(3))) unsigned int*)l, 16, 0, 0);
}

// monotone float->uint key: preserves order for atomicMax; 0 is below all keys
__device__ __forceinline__ unsigned fkey(float f) {
    unsigned u = __float_as_uint(f);
    return (u & 0x80000000u) ? ~u : (u | 0x80000000u);
}
__device__ __forceinline__ float funkey(unsigned k) {
    unsigned u = (k & 0x80000000u) ? (k ^ 0x80000000u) : ~k;
    return __uint_as_float(u);
}

// ---------------------------------------------------------------------------
// prep: [0,4096) convw (Q sec pre-scaled, float4->half4),
//       [4096,8192) xpose 64x64, [8192,8320) initmax, [8320,8324) bqs.
__global__ __launch_bounds__(256) void prep_kernel(
    const float* __restrict__ Wq, const float* __restrict__ Wk,
    const float* __restrict__ Wv, const float* __restrict__ Wo,
    _Float16* __restrict__ Wcat,
    const float* __restrict__ x, _Float16* __restrict__ xT,
    unsigned* __restrict__ omax,
    const float* __restrict__ bq, float* __restrict__ bqs)
{
    __shared__ float tile[64][65];
    const int bid = blockIdx.x;
    if (bid < 4096) {
        int i4 = bid * 256 + threadIdx.x;        // float4 index, 0 .. 1M
        int sec = i4 >> 18;
        int off4 = i4 & ((1 << 18) - 1);
        const float* src = (sec == 0) ? Wq : (sec == 1) ? Wk
                          : (sec == 2) ? Wv : Wo;
        float4 v = ((const float4*)src)[off4];
        if (sec == 0) {
            v.x *= QSCALE; v.y *= QSCALE; v.z *= QSCALE; v.w *= QSCALE;
        }
        half4 h = {(_Float16)v.x, (_Float16)v.y, (_Float16)v.z, (_Float16)v.w};
        *(half4*)(Wcat + (size_t)i4 * 4) = h;
    } else if (bid < 8192) {
        int idx = bid - 4096;                    // 32 b x 16 h-tiles x 8 t-tiles
        int b = idx >> 7, h0 = ((idx >> 3) & 15) * 64, t0 = (idx & 7) * 64;
        int tx = threadIdx.x & 15, ty = threadIdx.x >> 4;   // 16x16
        const float* xb = x + ((size_t)b * HID + h0) * TT + t0;
        for (int p = 0; p < 4; p++) {
            int r = ty + 16 * p;
            float4 v = *(const float4*)(xb + (size_t)r * TT + tx * 4);
            tile[r][tx * 4 + 0] = v.x;
            tile[r][tx * 4 + 1] = v.y;
            tile[r][tx * 4 + 2] = v.z;
            tile[r][tx * 4 + 3] = v.w;
        }
        __syncthreads();
        int hc = (threadIdx.x & 7) * 8, tb = threadIdx.x >> 3;  // 8 x 32
        for (int rd = 0; rd < 2; rd++) {
            int tt = tb + 32 * rd;
            half8 pk;
            for (int k = 0; k < 8; k++)
                pk[k] = (_Float16)tile[hc + k][tt];
            *(half8*)(xT + ((size_t)b * TT + t0 + tt) * HID + h0 + hc) = pk;
        }
    } else if (bid < 8320) {
        omax[(bid - 8192) * 256 + threadIdx.x] = 0u;
    } else {
        int i = (bid - 8320) * 256 + threadIdx.x;   // 0..1023
        bqs[i] = bq[i] * QSCALE;
    }
}

// ---------------------------------------------------------------------------
// Shared 8-phase machinery (R14-verified ledger).
#define PH_PRE do { \
    __builtin_amdgcn_s_barrier(); \
    asm volatile("s_waitcnt lgkmcnt(0)" ::: "memory"); \
    __builtin_amdgcn_sched_barrier(0); \
    __builtin_amdgcn_s_setprio(1); \
} while (0)

#define PH_POST(N) do { \
    __builtin_amdgcn_s_setprio(0); \
    asm volatile("s_waitcnt vmcnt(" #N ")" ::: "memory"); \
    __builtin_amdgcn_s_barrier(); \
} while (0)

#define LDA(P, MH) do { \
    const _Float16* ab_ = lds + (P) * 16384 + (MH) * 8192 + aoff; \
    af[0][0] = *(const half8*)(ab_ + pb0); \
    af[0][1] = *(const half8*)(ab_ + pb1); \
    af[1][0] = *(const half8*)(ab_ + 1024 + pb0); \
    af[1][1] = *(const half8*)(ab_ + 1024 + pb1); \
    af[2][0] = *(const half8*)(ab_ + 2048 + pb0); \
    af[2][1] = *(const half8*)(ab_ + 2048 + pb1); \
    af[3][0] = *(const half8*)(ab_ + 3072 + pb0); \
    af[3][1] = *(const half8*)(ab_ + 3072 + pb1); \
} while (0)

#define LDB(P, NH) do { \
    const _Float16* bb_ = lds + 32768 + (P) * 16384 + (NH) * 8192 + boff; \
    bf[NH][0][0] = *(const half8*)(bb_ + pb0); \
    bf[NH][0][1] = *(const half8*)(bb_ + pb1); \
    bf[NH][1][0] = *(const half8*)(bb_ + 1024 + pb0); \
    bf[NH][1][1] = *(const half8*)(bb_ + 1024 + pb1); \
} while (0)

#define MFMAQ(MH, NH) do { \
    _Pragma("unroll") \
    for (int j_ = 0; j_ < 4; ++j_) { \
        _Pragma("unroll") \
        for (int n_ = 0; n_ < 2; ++n_) { \
            floatx4 c_ = acc[(MH) * 4 + j_][(NH) * 2 + n_]; \
            c_ = __builtin_amdgcn_mfma_f32_16x16x32_f16( \
                af[j_][0], bf[NH][n_][0], c_, 0, 0, 0); \
            c_ = __builtin_amdgcn_mfma_f32_16x16x32_f16( \
                af[j_][1], bf[NH][n_][1], c_, 0, 0, 0); \
            acc[(MH) * 4 + j_][(NH) * 2 + n_] = c_; \
        } \
    } \
} while (0)

// gemm2's single-tile mainloop (K = 1024, 16 K-tiles), R14-identical.
#define STAGE_A(P, MH, K0) do { \
    _Float16* d_ = lds + (P) * 16384 + (MH) * 8192 + wst; \
    gload16(ag + (MH) * 65536 + (K0), d_); \
    gload16(ag + 131072 + (MH) * 65536 + (K0), d_ + 4096); \
} while (0)

#define STAGE_B(P, NH, K0) do { \
    _Float16* d_ = lds + 32768 + (P) * 16384 + (NH) * 8192 + wst; \
    gload16(bg + (NH) * 32768 + (K0), d_); \
    gload16(bg + 131072 + (NH) * 32768 + (K0), d_ + 4096); \
} while (0)

__device__ __forceinline__ void mainloop256(
    const _Float16* __restrict__ Ag,   // A + m0*1024 (rows m, K contig)
    const _Float16* __restrict__ Bg,   // act + n0*1024 (rows n, K contig)
    _Float16* lds, floatx4 acc[8][4], int tid)
{
    const int lane = tid & 63;
    const int w = tid >> 6, wr = w >> 2, wc = w & 3;
    const int l15 = lane & 15, quad = lane >> 4;
    const int pa = quad ^ (l15 & 7);
    const int pb0 = pa * 8, pb1 = (pa ^ 4) * 8;
    const int aoff = (wr * 64 + l15) * 64;
    const int boff = (wc * 32 + l15) * 64;
    const int wst = w * 512;                    // wave-uniform LDS stage base
    const int r = tid >> 3;                     // 0..63
    const int sg = (tid & 7) ^ (r & 7);         // pre-swizzled source granule
    const int nbase = ((r >> 5) << 6) + (r & 31);
    const _Float16* ag = Ag + (size_t)r * 1024 + sg * 8;
    const _Float16* bg = Bg + (size_t)nbase * 1024 + sg * 8;

    half8 af[4][2], bf[2][2][2];

    STAGE_A(0, 0, 0); STAGE_B(0, 0, 0); STAGE_B(0, 1, 0); STAGE_A(0, 1, 0);
    STAGE_A(1, 0, 64); STAGE_B(1, 0, 64); STAGE_B(1, 1, 64);
    asm volatile("s_waitcnt vmcnt(10)" ::: "memory");
    __builtin_amdgcn_s_barrier();

    for (int i = 0; i < 7; ++i) {
        const int kb = i * 128 + 64;
        const int kn0 = kb + 64, kn1 = kb + 128;
        LDA(0, 0); LDB(0, 0); STAGE_A(1, 1, kb);
        PH_PRE; MFMAQ(0, 0); PH_POST(10);
        LDB(0, 1);            STAGE_A(0, 0, kn0);
        PH_PRE; MFMAQ(0, 1); PH_POST(10);
        LDA(0, 1);            STAGE_B(0, 0, kn0);
        PH_PRE; MFMAQ(1, 1); PH_POST(10);
                              STAGE_B(0, 1, kn0);
        PH_PRE; MFMAQ(1, 0); PH_POST(10);
        LDA(1, 0); LDB(1, 0); STAGE_A(0, 1, kn0);
        PH_PRE; MFMAQ(0, 0); PH_POST(10);
        LDB(1, 1);            STAGE_A(1, 0, kn1);
        PH_PRE; MFMAQ(0, 1); PH_POST(10);
        LDA(1, 1);            STAGE_B(1, 0, kn1);
        PH_PRE; MFMAQ(1, 1); PH_POST(10);
                              STAGE_B(1, 1, kn1);
        PH_PRE; MFMAQ(1, 0); PH_POST(10);
    }
    LDA(0, 0); LDB(0, 0); STAGE_A(1, 1, 960);
    PH_PRE; MFMAQ(0, 0); PH_POST(10);
    LDB(0, 1);
    PH_PRE; MFMAQ(0, 1); PH_POST(8);
    LDA(0, 1);
    PH_PRE; MFMAQ(1, 1); PH_POST(6);
    PH_PRE; MFMAQ(1, 0); PH_POST(4);
    LDA(1, 0); LDB(1, 0);
    PH_PRE; MFMAQ(0, 0); PH_POST(2);
    LDB(1, 1);
    PH_PRE; MFMAQ(0, 1); PH_POST(0);
    LDA(1, 1);
    PH_PRE; MFMAQ(1, 1); MFMAQ(1, 0);
    __builtin_amdgcn_s_setprio(0);
}

// ---------------------------------------------------------------------------
// Chained gemm1: grid 256, block = (n0,b) x 3 consecutive m-tiles, one
// virtual 48-K-tile pipeline. Stage addressing: A m-slice = (j>>4)*256 rows
// (slices are consecutive in Wcat), B k-offset = (j&15)*64.
#define AOF(J) (((J) >> 4) * 262144 + ((J) & 15) * 64)
#define BOF(J) (((J) & 15) * 64)

#define SA1(P, MH, J) do { \
    _Float16* d_ = lds + (P) * 16384 + (MH) * 8192 + wst; \
    gload16(ag + (MH) * 65536 + AOF(J), d_); \
    gload16(ag + 131072 + (MH) * 65536 + AOF(J), d_ + 4096); \
} while (0)

#define SB1(P, NH, J) do { \
    _Float16* d_ = lds + 32768 + (P) * 16384 + (NH) * 8192 + wst; \
    gload16(bg + (NH) * 32768 + BOF(J), d_); \
    gload16(bg + 131072 + (NH) * 32768 + BOF(J), d_ + 4096); \
} while (0)

#define PAIR(I) do { \
    const int j1 = 2 * (I) + 1, j2 = 2 * (I) + 2, j3 = 2 * (I) + 3; \
    LDA(0, 0); LDB(0, 0); SA1(1, 1, j1); \
    PH_PRE; MFMAQ(0, 0); PH_POST(10); \
    LDB(0, 1);            SA1(0, 0, j2); \
    PH_PRE; MFMAQ(0, 1); PH_POST(10); \
    LDA(0, 1);            SB1(0, 0, j2); \
    PH_PRE; MFMAQ(1, 1); PH_POST(10); \
                          SB1(0, 1, j2); \
    PH_PRE; MFMAQ(1, 0); PH_POST(10); \
    LDA(1, 0); LDB(1, 0); SA1(0, 1, j2); \
    PH_PRE; MFMAQ(0, 0); PH_POST(10); \
    LDB(1, 1);            SA1(1, 0, j3); \
    PH_PRE; MFMAQ(0, 1); PH_POST(10); \
    LDA(1, 1);            SB1(1, 0, j3); \
    PH_PRE; MFMAQ(1, 1); PH_POST(10); \
                          SB1(1, 1, j3); \
    PH_PRE; MFMAQ(1, 0); PH_POST(10); \
} while (0)

__global__ __launch_bounds__(512, 2) void gemm1_kernel(
    const _Float16* __restrict__ Wcat,
    const float* __restrict__ bqs, const float* __restrict__ bk,
    const float* __restrict__ bv,
    const _Float16* __restrict__ xT,
    _Float16* __restrict__ QT, _Float16* __restrict__ KT,
    _Float16* __restrict__ Vb)
{
    __shared__ __align__(16) _Float16 smem[65536];   // 128 KiB
    _Float16* lds = smem;
    const int tid = threadIdx.x;
    const int id = blockIdx.x;
    const int xcd = id & 7, slot = id >> 3;      // slot 0..31
    const int grp = xcd + 8 * (slot >> 2);       // 0..63 = n0i + 2*b
    const int mseg = slot & 3;                   // 3 m-tiles: mseg*3 .. +2
    const int n0 = (grp & 1) * 256;
    const int bb = grp >> 1;
    const int lane = tid & 63;
    const int w = tid >> 6, wr = w >> 2, wc = w & 3;
    const int l15 = lane & 15, quad = lane >> 4;
    const int pa = quad ^ (l15 & 7);
    const int pb0 = pa * 8, pb1 = (pa ^ 4) * 8;
    const int aoff = (wr * 64 + l15) * 64;
    const int boff = (wc * 32 + l15) * 64;
    const int wst = w * 512;
    const int r = tid >> 3;
    const int sg = (tid & 7) ^ (r & 7);
    const int nbase = ((r >> 5) << 6) + (r & 31);
    const _Float16* ag = Wcat + (size_t)(mseg * 768 + r) * 1024 + sg * 8;
    const _Float16* bg = xT + ((size_t)bb * TT + n0 + nbase) * 1024 + sg * 8;

    floatx4 acc[8][4] = {};
    half8 af[4][2], bf[2][2][2];

    // LDS-free epilogue for m-tile (mseg*3 + v); zeroes acc for the next tile.
    auto epi = [&](int v) {
        const int mt = mseg * 3 + v;
        const int sec = mt >> 2;                 // 0=q 1=k 2=v
        const int mo = (mt & 3) * 256 + wr * 128;
        if (sec < 2) {
            const float* bias = (sec == 0) ? bqs : bk;
            _Float16* dst = (sec == 0) ? QT : KT;
            _Float16* drow = dst + ((size_t)bb * TT + n0 + wc * 64 + l15) * HID
                             + mo + quad * 4;
            for (int mi = 0; mi < 8; ++mi) {
                float bs[4];
                for (int rr = 0; rr < 4; ++rr)
                    bs[rr] = bias[mo + mi * 16 + quad * 4 + rr];
                for (int ni = 0; ni < 4; ++ni) {
                    half4 pk;
                    for (int rr = 0; rr < 4; ++rr)
                        pk[rr] = (_Float16)(acc[mi][ni][rr] + bs[rr]);
                    *(half4*)(drow + (size_t)(ni * 16) * HID + mi * 16) = pk;
                    acc[mi][ni] = (floatx4){0.f, 0.f, 0.f, 0.f};
                }
            }
        } else {
            for (int mi = 0; mi < 8; ++mi) {
                float bs[4];
                for (int rr = 0; rr < 4; ++rr)
                    bs[rr] = bv[mo + mi * 16 + quad * 4 + rr];
                for (int ni = 0; ni < 4; ++ni) {
                    int t = n0 + wc * 64 + ni * 16 + l15;
                    for (int rr = 0; rr < 4; ++rr) {
                        int o = mo + mi * 16 + quad * 4 + rr;
                        Vb[((size_t)bb * HID + o) * TT + t] =
                            (_Float16)(acc[mi][ni][rr] + bs[rr]);
                    }
                    acc[mi][ni] = (floatx4){0.f, 0.f, 0.f, 0.f};
                }
            }
        }
    };

    // prologue: virtual tile 0 fully + tile 1 minus A.mh1
    SA1(0, 0, 0); SB1(0, 0, 0); SB1(0, 1, 0); SA1(0, 1, 0);
    SA1(1, 0, 1); SB1(1, 0, 1); SB1(1, 1, 1);
    asm volatile("s_waitcnt vmcnt(10)" ::: "memory");
    __builtin_amdgcn_s_barrier();

    for (int ii = 0; ii < 8; ++ii) PAIR(ii);
    epi(0);
    for (int ii = 8; ii < 16; ++ii) PAIR(ii);
    epi(1);
    for (int ii = 16; ii < 23; ++ii) PAIR(ii);
    // drain pair (virtual tiles 46, 47)
    LDA(0, 0); LDB(0, 0); SA1(1, 1, 47);
    PH_PRE; MFMAQ(0, 0); PH_POST(10);
    LDB(0, 1);
    PH_PRE; MFMAQ(0, 1); PH_POST(8);
    LDA(0, 1);
    PH_PRE; MFMAQ(1, 1); PH_POST(6);
    PH_PRE; MFMAQ(1, 0); PH_POST(4);
    LDA(1, 0); LDB(1, 0);
    PH_PRE; MFMAQ(0, 0); PH_POST(2);
    LDB(1, 1);
    PH_PRE; MFMAQ(0, 1); PH_POST(0);
    LDA(1, 1);
    PH_PRE; MFMAQ(1, 1); MFMAQ(1, 0);
    __builtin_amdgcn_s_setprio(0);
    epi(2);
}

// ---------------------------------------------------------------------------
// attention (R9 inner loops, unchanged). 1-D grid 2048, XCD-clustered.
__global__ __launch_bounds__(256) void attn_kernel(
    const _Float16* __restrict__ QT, const _Float16* __restrict__ KT,
    const _Float16* __restrict__ Vb, const int* __restrict__ mask,
    _Float16* __restrict__ OcT)
{
    __shared__ __align__(16) _Float16 kvbuf[4 * 4096];
    __shared__ __align__(16) _Float16 ps[2 * 4096];  // [qt][q][t] swizzled
    __shared__ __align__(16) float msf[2][64];       // clamp hi bound per t

    const int id = blockIdx.x;
    const int xcd = id & 7, slot = id >> 3;      // slot 0..255
    const int grp = xcd + 8 * (slot >> 2);       // 0..511 = hd + 16*b
    const int q0 = (slot & 3) * 128;
    const int hd = grp & 15, b = grp >> 4;
    const int tid = threadIdx.x;
    const int lane = tid & 63, wid = tid >> 6;
    const int l15 = lane & 15, quad = lane >> 4;

    const _Float16* QTb = QT + ((size_t)b * TT + q0) * HID + hd * 64;
    const _Float16* KTb = KT + (size_t)b * TT * HID + hd * 64;
    const _Float16* Vbb = Vb + ((size_t)b * HID + hd * 64) * TT;
    const int* mb = mask + b * TT;

    const int srow = lane >> 3;                 // 0..7 == row&7
    const int sg = (lane & 7) ^ srow;
    const int pa = quad ^ (l15 & 7);
    const int pz = l15 & 7;

    for (int qt = 0; qt < 2; qt++)
        for (int p = 0; p < 2; p++) {
            int r = p * 32 + wid * 8 + srow;
            gload16(QTb + (size_t)(qt * 64 + r) * HID + sg * 8,
                    kvbuf + qt * 4096 + (p * 32 + wid * 8) * 64);
        }
    __syncthreads();
    half8 bq[2][2];
    for (int qt = 0; qt < 2; qt++) {
        bq[qt][0] = *(half8*)(kvbuf + qt * 4096 + (wid * 16 + l15) * 64 + pa * 8);
        bq[qt][1] = *(half8*)(kvbuf + qt * 4096 + (wid * 16 + l15) * 64 + (pa ^ 4) * 8);
    }
    __syncthreads();

    auto stage = [&](int jcn, int bufn) {
        int t0n = jcn * 64;
        _Float16* kd = kvbuf + bufn * 4096;
        _Float16* vd = kvbuf + (2 + bufn) * 4096;
        for (int p = 0; p < 2; p++) {
            int r = p * 32 + wid * 8 + srow;
            gload16(KTb + (size_t)(t0n + r) * HID + sg * 8,
                    kd + (p * 32 + wid * 8) * 64);
            gload16(Vbb + (size_t)r * TT + t0n + sg * 8,
                    vd + (p * 32 + wid * 8) * 64);
        }
        if (tid < 64) msf[bufn][tid] = mb[t0n + tid] ? SB2 : -SB2;
    };

    stage(0, 0);

    floatx4 oacc[2][4] = {};
    float rs[2] = {0.f, 0.f};
    const float lo = -SB2;

    for (int jc = 0; jc < 8; jc++) {
        const int cur = jc & 1;
        __syncthreads();
        if (jc < 7) stage(jc + 1, 1 - cur);

        const _Float16* ks = kvbuf + cur * 4096;
        const _Float16* vs = kvbuf + (2 + cur) * 4096;

        for (int jt = 0; jt < 4; jt++) {
            half8 ka0 = *(half8*)(ks + (jt * 16 + l15) * 64 + pa * 8);
            half8 ka1 = *(half8*)(ks + (jt * 16 + l15) * 64 + (pa ^ 4) * 8);
            floatx4 hi = *(floatx4*)(&msf[cur][jt * 16 + quad * 4]);
            for (int qt = 0; qt < 2; qt++) {
                floatx4 sc = {0.f, 0.f, 0.f, 0.f};
                sc = __builtin_amdgcn_mfma_f32_16x16x32_f16(ka0, bq[qt][0], sc, 0, 0, 0);
                sc = __builtin_amdgcn_mfma_f32_16x16x32_f16(ka1, bq[qt][1], sc, 0, 0, 0);
                float e0 = __builtin_amdgcn_exp2f(fminf(fmaxf(sc[0], lo), hi[0]));
                float e1 = __builtin_amdgcn_exp2f(fminf(fmaxf(sc[1], lo), hi[1]));
                float e2 = __builtin_amdgcn_exp2f(fminf(fmaxf(sc[2], lo), hi[2]));
                float e3 = __builtin_amdgcn_exp2f(fminf(fmaxf(sc[3], lo), hi[3]));
                rs[qt] += (e0 + e1) + (e2 + e3);
                unsigned uA = __builtin_bit_cast(
                    unsigned, __builtin_amdgcn_cvt_pkrtz(e0, e1));
                unsigned uB = __builtin_bit_cast(
                    unsigned, __builtin_amdgcn_cvt_pkrtz(e2, e3));
                uintx2 uv = {uA, uB};
                half4 pk = __builtin_bit_cast(half4, uv);
                int g = jt * 2 + (quad >> 1);
                *(half4*)(ps + qt * 4096 + (wid * 16 + l15) * 64 + (g ^ pz) * 8 +
                          (quad & 1) * 4) = pk;
            }
        }
        for (int kc = 0; kc < 2; kc++) {
            int g = kc * 4 + quad;
            half8 bv8[4];
            for (int d4 = 0; d4 < 4; d4++)
                bv8[d4] = *(half8*)(vs + (d4 * 16 + l15) * 64 + (g ^ pz) * 8);
            for (int qt = 0; qt < 2; qt++) {
                half8 ap = *(half8*)(ps + qt * 4096 + (wid * 16 + l15) * 64 +
                                     (g ^ pz) * 8);
                for (int d4 = 0; d4 < 4; d4++)
                    oacc[qt][d4] = __builtin_amdgcn_mfma_f32_16x16x32_f16(
                        ap, bv8[d4], oacc[qt][d4], 0, 0, 0);
            }
        }
    }

    for (int qt = 0; qt < 2; qt++) {
        float s = rs[qt];
        s += __shfl_xor(s, 16, 64);
        s += __shfl_xor(s, 32, 64);
        s = 1.0f / s;
        float inv[4];
        for (int r = 0; r < 4; r++) inv[r] = __shfl(s, quad * 4 + r, 64);
        for (int d4 = 0; d4 < 4; d4++)
            for (int r = 0; r < 4; r++) {
                int t = q0 + qt * 64 + wid * 16 + quad * 4 + r;
                int c = hd * 64 + d4 * 16 + l15;
                OcT[((size_t)b * TT + t) * HID + c] =
                    (_Float16)(oacc[qt][d4][r] * inv[r]);
            }
    }
}

// ---------------------------------------------------------------------------
// gemm2. 1-D grid 256, XCD-clustered (4 m-tiles per n-group).
__global__ __launch_bounds__(512, 2) void gemm2_kernel(
    const _Float16* __restrict__ Wo16, const _Float16* __restrict__ OcT,
    unsigned* __restrict__ omax)
{
    __shared__ __align__(16) _Float16 smem[65536];
    _Float16* lds = smem;
    const int tid = threadIdx.x;
    const int id = blockIdx.x;
    const int xcd = id & 7, slot = id >> 3;      // slot 0..31
    const int grp = xcd + 8 * (slot >> 2);       // 0..63 = n0i + 2*b
    const int m0 = (slot & 3) * 256;
    const int n0 = (grp & 1) * 256;
    const int bb = grp >> 1;
    const int lane = tid & 63;
    const int w = tid >> 6, wr = w >> 2;
    const int l15 = lane & 15, quad = lane >> 4;

    floatx4 acc[8][4] = {};
    mainloop256(Wo16 + (size_t)m0 * 1024,
                OcT + ((size_t)bb * TT + n0) * HID, lds, acc, tid);

    for (int mi = 0; mi < 8; ++mi)
        for (int rr = 0; rr < 4; ++rr) {
            float v = acc[mi][0][rr];
            v = fmaxf(v, acc[mi][1][rr]);
            v = fmaxf(v, acc[mi][2][rr]);
            v = fmaxf(v, acc[mi][3][rr]);
            for (int d = 1; d < 16; d <<= 1)
                v = fmaxf(v, __shfl_xor(v, d, 64));
            if (l15 == 0) {
                int o = m0 + wr * 128 + mi * 16 + quad * 4 + rr;
                atomicMax(&omax[bb * HID + o], fkey(v));
            }
        }
}

__global__ __launch_bounds__(256) void final_kernel(
    const unsigned* __restrict__ omax, const float* __restrict__ bo,
    float* __restrict__ out)
{
    int i = blockIdx.x * 256 + threadIdx.x;   // 0 .. 32767
    out[i] = funkey(omax[i]) + bo[i & 1023];
}

// ---------------------------------------------------------------------------
extern "C" void kernel_launch(void* const* d_in, const int* in_sizes, int n_in,
                              void* d_out, int out_size, void* d_ws, size_t ws_size,
                              hipStream_t stream)
{
    const float* x  = (const float*)d_in[0];
    const int* mask = (const int*)d_in[1];
    const float* Wq = (const float*)d_in[2];
    const float* bq = (const float*)d_in[3];
    const float* Wk = (const float*)d_in[4];
    const float* bk = (const float*)d_in[5];
    const float* Wv = (const float*)d_in[6];
    const float* bv = (const float*)d_in[7];
    const float* Wo = (const float*)d_in[8];
    const float* bo = (const float*)d_in[9];
    float* out = (float*)d_out;

    char* ws = (char*)d_ws;
    _Float16* Wcat = (_Float16*)(ws);                      //   8 MiB (q,k,v,o)
    _Float16* xT   = (_Float16*)(ws + (8ull  << 20));      //  32 MiB
    _Float16* QT   = (_Float16*)(ws + (40ull << 20));      //  32 MiB
    _Float16* KT   = (_Float16*)(ws + (72ull << 20));      //  32 MiB
    _Float16* Vb   = (_Float16*)(ws + (104ull << 20));     //  32 MiB
    _Float16* OcT  = (_Float16*)(ws + (136ull << 20));     //  32 MiB
    unsigned* omax = (unsigned*)(ws + (168ull << 20));     // 128 KiB
    float*    bqs  = (float*)(ws + (168ull << 20) + (128ull << 10)); // 4 KiB

    prep_kernel<<<8324, 256, 0, stream>>>(Wq, Wk, Wv, Wo, Wcat, x, xT, omax,
                                          bq, bqs);
    gemm1_kernel<<<256, 512, 0, stream>>>(Wcat, bqs, bk, bv, xT, QT, KT, Vb);
    attn_kernel<<<2048, 256, 0, stream>>>(QT, KT, Vb, mask, OcT);
    gemm2_kernel<<<256, 512, 0, stream>>>(Wcat + (3ull << 20), OcT, omax);
    final_kernel<<<128, 256, 0, stream>>>(omax, bo, out);
}